// Round 6
// baseline (140.657 us; speedup 1.0000x reference)
//
#include <hip/hip_runtime.h>
#include <hip/hip_bf16.h>

// InfoNCE loss, N=4096, D=1024, TEMP=0.07.
// loss = mean_i( -pos_i + lse_i ), lse over sim rows with diagonal masked.
// Fixed-max LSE (rows unit-norm -> sim <= 1/T): partials are order-independent
// -> atomicAdd across tiles; symmetry via 256x128 tiles with Jh >= 2I.
//
// MX-fp8 datapath: z cast to OCP e4m3 (pos stays fp32-exact); sim tiles via
// mfma_scale_f32_32x32x64_f8f6f4 with unit scales (E8M0=127). 256(M)x128(N)
// tile, 4 waves (2Mx2N, each 128x64 out), BK=64 ring-of-3 LDS slots (72 KiB
// -> 2 blocks/CU), depth-2 prefetch, counted vmcnt(6), one s_barrier/step,
// XOR-swizzled LDS reads with inverse-swizzled global_load_lds sources.

typedef __attribute__((ext_vector_type(4))) int i32x4;
typedef __attribute__((ext_vector_type(8))) int i32x8;
typedef __attribute__((ext_vector_type(16))) float f32x16;

#define NN 4096
#define TWO_N 8192
#define DIM 1024
#define TEMP_INV 14.285714285714286f
#define EXP_SCALE 20.609929155566303f /* log2(e)/0.07 */
#define NJT 64     /* N-tiles of 128 */
#define NBLK 1056  /* sum_I (64-2I); 1056 % 8 == 0 -> bijective XCD swizzle */
#define SLOTB 24576 /* bytes per slot: A 256x64B + B 128x64B */

#define GLD16(g, l)                                                          \
  __builtin_amdgcn_global_load_lds(                                          \
      (const __attribute__((address_space(1))) void*)(g),                    \
      (__attribute__((address_space(3))) void*)(l), 16, 0, 0)

// Fused: fp32->fp8(e4m3) cast of z=[z1;z2] AND pos=dot(z1,z2)/T in fp32.
__global__ __launch_bounds__(256) void prep_kernel(
    const float* __restrict__ z1, const float* __restrict__ z2,
    unsigned int* __restrict__ zf8, float* __restrict__ pos) {
  const int row = blockIdx.x, t = threadIdx.x;
  float4 a = ((const float4*)(z1 + (size_t)row * DIM))[t];
  float4 b = ((const float4*)(z2 + (size_t)row * DIM))[t];
  int wa = __builtin_amdgcn_cvt_pk_fp8_f32(a.x, a.y, 0, false);
  wa = __builtin_amdgcn_cvt_pk_fp8_f32(a.z, a.w, wa, true);
  int wb = __builtin_amdgcn_cvt_pk_fp8_f32(b.x, b.y, 0, false);
  wb = __builtin_amdgcn_cvt_pk_fp8_f32(b.z, b.w, wb, true);
  zf8[(size_t)row * (DIM / 4) + t] = (unsigned int)wa;
  zf8[(size_t)(NN + row) * (DIM / 4) + t] = (unsigned int)wb;
  float s = a.x * b.x + a.y * b.y + a.z * b.z + a.w * b.w;
#pragma unroll
  for (int off = 1; off < 64; off <<= 1) s += __shfl_xor(s, off);
  __shared__ float tmp[4];
  if ((t & 63) == 0) tmp[t >> 6] = s;
  __syncthreads();
  if (t == 0) pos[row] = (tmp[0] + tmp[1] + tmp[2] + tmp[3]) * TEMP_INV;
}

__global__ __launch_bounds__(256, 2) void lse_kernel(
    const unsigned char* __restrict__ zb8, float* __restrict__ rowsum) {
  __shared__ unsigned char lds[3 * SLOTB];  // 72 KiB -> 2 blocks/CU
  // ---- tile decode: XCD swizzle -> (I, Jh) with Jh >= 2I ----
  int u = ((int)blockIdx.x & 7) * (NBLK / 8) + ((int)blockIdx.x >> 3);
  int I = 0, rem = u;
  while (rem >= NJT - 2 * I) { rem -= NJT - 2 * I; ++I; }
  const int Jh = 2 * I + rem;
  const int rowA0 = I * 256, colB0 = Jh * 128;
  const bool straddle = (Jh >> 1) == I;  // tile within I's diagonal 256-block

  const int t = threadIdx.x;
  const int wave = t >> 6, lane = t & 63;
  const int wm = wave >> 1, wn = wave & 1;  // 2M x 2N waves, 128x64 out each
  const int l31 = lane & 31, kh = lane >> 5;

  // ---- staging: 4 A-chunks + 2 B-chunks (16B each) per thread per slot ----
  // slot layout (bytes): A[256 rows][64] at 0, B[128][64] at 16384. Chunk c:
  // row=c>>2, phys 16B-slot p=c&3 holds logical k16 = p ^ ((row>>1)&3)
  // (inverse of the read-side XOR). LDS dest linear (wave-uniform + lane*16).
  int oA[4], oB[2];
#pragma unroll
  for (int i = 0; i < 4; ++i) {
    int c = (i * 4 + wave) * 64 + lane, row = c >> 2, p = c & 3;
    oA[i] = (rowA0 + row) * DIM + (p ^ ((row >> 1) & 3)) * 16;
  }
#pragma unroll
  for (int i = 0; i < 2; ++i) {
    int c = (i * 4 + wave) * 64 + lane, row = c >> 2, p = c & 3;
    oB[i] = (colB0 + row) * DIM + (p ^ ((row >> 1) & 3)) * 16;
  }

  f32x16 acc[4][2];
#pragma unroll
  for (int m = 0; m < 4; ++m)
#pragma unroll
    for (int n = 0; n < 2; ++n)
#pragma unroll
      for (int r = 0; r < 16; ++r) acc[m][n][r] = 0.f;

#define STAGE(dst_, k_)                                                       \
  {                                                                           \
    const unsigned char* gk = zb8 + (size_t)((k_) & 15) * 64;                 \
    GLD16(gk + oA[0], (dst_) + (0 * 4 + wave) * 1024);                        \
    GLD16(gk + oA[1], (dst_) + (1 * 4 + wave) * 1024);                        \
    GLD16(gk + oA[2], (dst_) + (2 * 4 + wave) * 1024);                        \
    GLD16(gk + oA[3], (dst_) + (3 * 4 + wave) * 1024);                        \
    GLD16(gk + oB[0], (dst_) + 16384 + (0 * 4 + wave) * 1024);                \
    GLD16(gk + oB[1], (dst_) + 16384 + (1 * 4 + wave) * 1024);                \
  }

  // read-side swizzled 16B slot: frag row r (local), logical k16 -> phys
  // byte = r*64 + (k16 ^ ((r>>1)&3))*16. Frag bytes 0..15 = k16 (=2*kh),
  // 16..31 = k16+1 (adjacent k), per-lane k = kh*32 + byte.
#define READ_FRAG(F, base_, rloc_)                                            \
  {                                                                           \
    const unsigned char* rb_ = (base_) + (rloc_) * 64;                        \
    const int cls_ = ((rloc_) >> 1) & 3;                                      \
    i32x4 lo_ = *(const i32x4*)(rb_ + (((2 * kh) ^ cls_) << 4));              \
    i32x4 hi_ = *(const i32x4*)(rb_ + (((2 * kh + 1) ^ cls_) << 4));          \
    F[0] = lo_[0]; F[1] = lo_[1]; F[2] = lo_[2]; F[3] = lo_[3];               \
    F[4] = hi_[0]; F[5] = hi_[1]; F[6] = hi_[2]; F[7] = hi_[3];               \
  }

  unsigned char* s0 = lds;              // current slot
  unsigned char* s1 = lds + SLOTB;      // next
  unsigned char* s2 = lds + 2 * SLOTB;  // stage target

  STAGE(s0, 0);
  STAGE(s1, 1);

#pragma unroll 1
  for (int s = 0; s < DIM / 64; ++s) {
    // gate: 6 newest (slot s+1) stay in flight; slot s must be landed.
    asm volatile("s_waitcnt vmcnt(6)" ::: "memory");
    asm volatile("s_waitcnt lgkmcnt(0)" ::: "memory");
    __builtin_amdgcn_s_barrier();  // publish slot s; free slot s-1 (=s2)
    __builtin_amdgcn_sched_barrier(0);
    STAGE(s2, s + 2);  // s>=14: dummy re-stage (k wraps), never read

    i32x8 bf[2];
#pragma unroll
    for (int n = 0; n < 2; ++n)
      READ_FRAG(bf[n], s0 + 16384, wn * 64 + n * 32 + l31);
    __builtin_amdgcn_s_setprio(1);
#pragma unroll
    for (int m = 0; m < 4; ++m) {
      i32x8 af;
      READ_FRAG(af, s0, wm * 128 + m * 32 + l31);
#pragma unroll
      for (int n = 0; n < 2; ++n)
        acc[m][n] = __builtin_amdgcn_mfma_scale_f32_32x32x64_f8f6f4(
            af, bf[n], acc[m][n], 0, 0, 0, 127, 0, 127);
    }
    __builtin_amdgcn_s_setprio(0);
    unsigned char* tmp_ = s0; s0 = s1; s1 = s2; s2 = tmp_;  // rotate ring
  }
  asm volatile("s_waitcnt vmcnt(0) lgkmcnt(0)" ::: "memory");  // drain dummies

  // ---- epilogue: e=exp((dot-1)/T), diag masked; row sums + col sums ----
  // C/D 32x32: col = lane&31, row = (reg&3) + 8*(reg>>2) + 4*(lane>>5).
  float csum[2] = {0.f, 0.f};
#pragma unroll
  for (int m = 0; m < 4; ++m) {
#pragma unroll
    for (int r = 0; r < 16; ++r) {
      const int grow = rowA0 + wm * 128 + m * 32 + (r & 3) + 8 * (r >> 2) + 4 * kh;
      float s = 0.f;
#pragma unroll
      for (int n = 0; n < 2; ++n) {
        const int gcol = colB0 + wn * 64 + n * 32 + l31;
        float e = exp2f((acc[m][n][r] - 1.0f) * EXP_SCALE);
        if (grow == gcol) e = 0.f;  // mask self-similarity
        s += e;
        csum[n] += e;
      }
      s += __shfl_xor(s, 1); s += __shfl_xor(s, 2); s += __shfl_xor(s, 4);
      s += __shfl_xor(s, 8); s += __shfl_xor(s, 16);
      if (l31 == 0) atomicAdd(&rowsum[grow], s);
    }
  }
  if (!straddle) {  // strictly-above tiles feed transposed rows via col sums
#pragma unroll
    for (int n = 0; n < 2; ++n) {
      float c = csum[n];
      c += __shfl_xor(c, 32);  // combine kh halves (same col, disjoint rows)
      if (lane < 32) atomicAdd(&rowsum[colB0 + wn * 64 + n * 32 + lane], c);
    }
  }
#undef READ_FRAG
#undef STAGE
}

__global__ __launch_bounds__(256) void finalize_kernel(
    const float* __restrict__ rowsum, const float* __restrict__ pos,
    float* __restrict__ out) {
  int t = threadIdx.x;
  float acc = 0.f;
  for (int i = t; i < TWO_N; i += 256)
    acc += TEMP_INV + logf(rowsum[i]) - pos[i & (NN - 1)];
#pragma unroll
  for (int off = 1; off < 64; off <<= 1) acc += __shfl_xor(acc, off);
  __shared__ float tmp[4];
  if ((t & 63) == 0) tmp[t >> 6] = acc;
  __syncthreads();
  if (t == 0) out[0] = (tmp[0] + tmp[1] + tmp[2] + tmp[3]) / (float)TWO_N;
}

extern "C" void kernel_launch(void* const* d_in, const int* in_sizes, int n_in,
                              void* d_out, int out_size, void* d_ws, size_t ws_size,
                              hipStream_t stream) {
  const float* z1 = (const float*)d_in[0];
  const float* z2 = (const float*)d_in[1];
  float* out = (float*)d_out;

  char* ws = (char*)d_ws;
  unsigned char* zf8 = (unsigned char*)ws;                  // 8 MB fp8 z
  float* rowsum = (float*)(ws + (size_t)TWO_N * DIM);       // 32 KB
  float* pos = (float*)(ws + (size_t)TWO_N * DIM + TWO_N * 4);  // 16 KB

  hipMemsetAsync(rowsum, 0, TWO_N * sizeof(float), stream);
  prep_kernel<<<NN, 256, 0, stream>>>(z1, z2, (unsigned int*)zf8, pos);
  lse_kernel<<<NBLK, 256, 0, stream>>>(zf8, rowsum);
  finalize_kernel<<<1, 256, 0, stream>>>(rowsum, pos, out);
}

// Round 7
// 137.783 us; speedup vs baseline: 1.0209x; 1.0209x over previous
//
#include <hip/hip_runtime.h>
#include <hip/hip_bf16.h>

// InfoNCE loss, N=4096, D=1024, TEMP=0.07.
// loss = mean_i( -pos_i + lse_i ), lse over sim rows with diagonal masked.
// Fixed-max LSE (rows unit-norm -> sim <= 1/T): partials are order-independent.
// Symmetry via 256x128 tiles with Jh >= 2I.
//
// R7: K-loop identical to R5 (bf16, ring-of-3 BK=32, vmcnt(6) gate, 72 KiB ->
// 2 blocks/CU, zero-conflict XOR swizzle). Epilogue ablation: NO global
// atomics -- plain stores into tile-private planes part[192][8192]
// (row partials: plane 2*Jh+wn; col partials: plane 128+2*I+wm; disjoint by
// construction), then a 32-block reduce folds planes -> rowsum.

typedef __attribute__((ext_vector_type(8))) short bf16x8;
typedef __attribute__((ext_vector_type(4))) float f32x4;

#define NN 4096
#define TWO_N 8192
#define DIM 1024
#define TEMP_INV 14.285714285714286f
#define EXP_SCALE 20.609929155566303f /* log2(e)/0.07 */
#define NJT 64    /* N-tiles of 128 */
#define NBLK 1056 /* sum_I (64-2I), I=0..31; 1056 % 8 == 0 -> bijective swizzle */
#define SLOT 12288 /* shorts per slot: A 256x32 + B 128x32 */
#define NPLANE 192

#define GLD16(g, l)                                                          \
  __builtin_amdgcn_global_load_lds(                                          \
      (const __attribute__((address_space(1))) void*)(g),                    \
      (__attribute__((address_space(3))) void*)(l), 16, 0, 0)

__device__ __forceinline__ unsigned short f2bf(float f) {
  unsigned int u = __float_as_uint(f);
  u += 0x7fffu + ((u >> 16) & 1u);  // RNE
  return (unsigned short)(u >> 16);
}

// Fused: fp32->bf16 cast of z=[z1;z2] AND pos[row]=dot(z1,z2)/T (one 32MB read).
__global__ __launch_bounds__(256) void prep_kernel(
    const float* __restrict__ z1, const float* __restrict__ z2,
    unsigned short* __restrict__ zb, float* __restrict__ pos) {
  const int row = blockIdx.x, t = threadIdx.x;
  float4 a = ((const float4*)(z1 + (size_t)row * DIM))[t];
  float4 b = ((const float4*)(z2 + (size_t)row * DIM))[t];
  ushort4 ua = {f2bf(a.x), f2bf(a.y), f2bf(a.z), f2bf(a.w)};
  ushort4 ub = {f2bf(b.x), f2bf(b.y), f2bf(b.z), f2bf(b.w)};
  ((ushort4*)(zb + (size_t)row * DIM))[t] = ua;
  ((ushort4*)(zb + (size_t)(NN + row) * DIM))[t] = ub;
  float s = a.x * b.x + a.y * b.y + a.z * b.z + a.w * b.w;
#pragma unroll
  for (int off = 1; off < 64; off <<= 1) s += __shfl_xor(s, off);
  __shared__ float tmp[4];
  if ((t & 63) == 0) tmp[t >> 6] = s;
  __syncthreads();
  if (t == 0) pos[row] = (tmp[0] + tmp[1] + tmp[2] + tmp[3]) * TEMP_INV;
}

__global__ __launch_bounds__(256, 2) void lse_kernel(
    const unsigned short* __restrict__ zb, float* __restrict__ part) {
  __shared__ unsigned short lds[3 * SLOT];  // 72 KiB -> 2 blocks/CU
  // ---- tile decode: XCD swizzle -> (I, Jh) with Jh >= 2I ----
  int u = ((int)blockIdx.x & 7) * (NBLK / 8) + ((int)blockIdx.x >> 3);
  int I = 0, rem = u;
  while (rem >= NJT - 2 * I) { rem -= NJT - 2 * I; ++I; }
  const int Jh = 2 * I + rem;
  const int rowA0 = I * 256, colB0 = Jh * 128;
  const bool straddle = (Jh >> 1) == I;  // tile lies within I's 256-block

  const int t = threadIdx.x;
  const int wave = t >> 6, lane = t & 63;
  const int wm = wave >> 1, wn = wave & 1;  // 2M x 2N waves, 128x64 out each
  const int lo = lane & 15, hi = lane >> 4;

  // ---- staging: per thread 4 A-chunks + 2 B-chunks (16B each) per slot ----
  // slot layout (shorts): A[256 rows][32] at 0, B[128][32] at 8192. Chunk c
  // (16B): row=c>>2, phys group p=c&3 holds logical lg = p ^ ((row>>1)&3)
  // (inverse of the read-side XOR). LDS dest = linear chunk order (wave-
  // uniform base; HW adds lane*16).
  int oA[4], oB[2];
  const int p = lane & 3;
#pragma unroll
  for (int i = 0; i < 4; ++i) {
    int c = (wave * 4 + i) * 64 + lane, row = c >> 2;
    oA[i] = (rowA0 + row) * DIM + (p ^ ((row >> 1) & 3)) * 8;
  }
#pragma unroll
  for (int i = 0; i < 2; ++i) {
    int c = (wave * 2 + i) * 64 + lane, row = c >> 2;
    oB[i] = (colB0 + row) * DIM + (p ^ ((row >> 1) & 3)) * 8;
  }

  // ---- compute-side ds_read offsets (shorts), swizzle applied on read ----
  const int sx = (hi ^ ((lo >> 1) & 3)) * 8;  // swizzled 16B group
  const int arow0 = wm * 128 + lo;            // + m*16
  const int brow0 = wn * 64 + lo;             // + n*16

  f32x4 acc[8][4];
#pragma unroll
  for (int m = 0; m < 8; ++m)
#pragma unroll
    for (int n = 0; n < 4; ++n) acc[m][n] = (f32x4){0.f, 0.f, 0.f, 0.f};

#define STAGE(dst_, k_)                                                       \
  {                                                                           \
    const unsigned short* gk = zb + (size_t)((k_) & 31) * 32;                 \
    GLD16(gk + oA[0], (dst_) + wave * 2048);                                  \
    GLD16(gk + oA[1], (dst_) + wave * 2048 + 512);                            \
    GLD16(gk + oA[2], (dst_) + wave * 2048 + 1024);                           \
    GLD16(gk + oA[3], (dst_) + wave * 2048 + 1536);                           \
    GLD16(gk + oB[0], (dst_) + 8192 + wave * 1024);                           \
    GLD16(gk + oB[1], (dst_) + 8192 + wave * 1024 + 512);                     \
  }

  unsigned short* s0 = lds;             // slot s (current)
  unsigned short* s1 = lds + SLOT;      // slot s+1
  unsigned short* s2 = lds + 2 * SLOT;  // slot s+2 (stage target)

  STAGE(s0, 0);
  STAGE(s1, 1);

#pragma unroll 1
  for (int s = 0; s < DIM / 32; ++s) {
    // gate: 6 newest (slot s+1) may stay in flight; slot s must be landed.
    asm volatile("s_waitcnt vmcnt(6)" ::: "memory");
    asm volatile("s_waitcnt lgkmcnt(0)" ::: "memory");  // prev frag reads done
    __builtin_amdgcn_s_barrier();  // publishes slot s; frees slot s-1 (=s2)
    __builtin_amdgcn_sched_barrier(0);
    STAGE(s2, s + 2);  // s>=30: dummy re-stage (k wraps), data never read

    bf16x8 bg[4];
#pragma unroll
    for (int n = 0; n < 4; ++n)
      bg[n] = *(const bf16x8*)(s0 + 8192 + (brow0 + n * 16) * 32 + sx);
    __builtin_amdgcn_s_setprio(1);
#pragma unroll
    for (int m = 0; m < 8; ++m) {
      bf16x8 af = *(const bf16x8*)(s0 + (arow0 + m * 16) * 32 + sx);
#pragma unroll
      for (int n = 0; n < 4; ++n)
        acc[m][n] = __builtin_amdgcn_mfma_f32_16x16x32_bf16(af, bg[n], acc[m][n], 0, 0, 0);
    }
    __builtin_amdgcn_s_setprio(0);
    unsigned short* tmp_ = s0; s0 = s1; s1 = s2; s2 = tmp_;  // rotate ring
  }
  asm volatile("s_waitcnt vmcnt(0) lgkmcnt(0)" ::: "memory");  // drain dummies

  // ---- epilogue: e=exp((dot-1)/T), diag masked; row/col partial sums ----
  // NO atomics: plain stores to tile-private planes.
  float* rplane = part + (size_t)(2 * Jh + wn) * TWO_N;        // row partials
  float* cplane = part + (size_t)(128 + 2 * I + wm) * TWO_N;   // col partials
  float csum[4] = {0.f, 0.f, 0.f, 0.f};
#pragma unroll
  for (int m = 0; m < 8; ++m) {
#pragma unroll
    for (int r = 0; r < 4; ++r) {
      const int grow = rowA0 + wm * 128 + m * 16 + hi * 4 + r;  // row=(lane>>4)*4+reg
      float s = 0.f;
#pragma unroll
      for (int n = 0; n < 4; ++n) {
        const int gcol = colB0 + wn * 64 + n * 16 + lo;         // col=lane&15
        float e = exp2f((acc[m][n][r] - 1.0f) * EXP_SCALE);
        if (grow == gcol) e = 0.f;  // mask self-similarity (straddle tiles)
        s += e;
        csum[n] += e;
      }
      s += __shfl_xor(s, 1); s += __shfl_xor(s, 2);
      s += __shfl_xor(s, 4); s += __shfl_xor(s, 8);
      if (lo == 0) rplane[grow] = s;  // 4 lanes, 128 distinct rows per wave
    }
  }
  if (!straddle) {  // strictly-above tiles feed transposed rows via col sums
#pragma unroll
    for (int n = 0; n < 4; ++n) {
      float s = csum[n];
      s += __shfl_xor(s, 16); s += __shfl_xor(s, 32);
      if (hi == 0) cplane[colB0 + wn * 64 + n * 16 + lo] = s;  // 16 lanes, 64 cols/wave
    }
  }
#undef STAGE
}

// Fold 192 partial planes -> rowsum[8192]. 32 blocks x 256 threads, 1 row each.
__global__ __launch_bounds__(256) void reduce_kernel(
    const float* __restrict__ part, float* __restrict__ rowsum) {
  const int i = blockIdx.x * 256 + threadIdx.x;
  float s = 0.f;
#pragma unroll 8
  for (int p = 0; p < NPLANE; ++p) s += part[(size_t)p * TWO_N + i];
  rowsum[i] = s;
}

__global__ __launch_bounds__(256) void finalize_kernel(
    const float* __restrict__ rowsum, const float* __restrict__ pos,
    float* __restrict__ out) {
  int t = threadIdx.x;
  float acc = 0.f;
  for (int i = t; i < TWO_N; i += 256)
    acc += TEMP_INV + logf(rowsum[i]) - pos[i & (NN - 1)];
#pragma unroll
  for (int off = 1; off < 64; off <<= 1) acc += __shfl_xor(acc, off);
  __shared__ float tmp[4];
  if ((t & 63) == 0) tmp[t >> 6] = acc;
  __syncthreads();
  if (t == 0) out[0] = (tmp[0] + tmp[1] + tmp[2] + tmp[3]) / (float)TWO_N;
}

extern "C" void kernel_launch(void* const* d_in, const int* in_sizes, int n_in,
                              void* d_out, int out_size, void* d_ws, size_t ws_size,
                              hipStream_t stream) {
  const float* z1 = (const float*)d_in[0];
  const float* z2 = (const float*)d_in[1];
  float* out = (float*)d_out;

  char* ws = (char*)d_ws;
  unsigned short* zb = (unsigned short*)ws;            // 16 MB bf16 z
  size_t off = (size_t)TWO_N * DIM * 2;
  float* part = (float*)(ws + off);                    // 6 MB: 192 x 8192 f32
  off += (size_t)NPLANE * TWO_N * 4;
  float* rowsum = (float*)(ws + off);                  // 32 KB
  off += TWO_N * 4;
  float* pos = (float*)(ws + off);                     // 16 KB

  hipMemsetAsync(part, 0, (size_t)NPLANE * TWO_N * 4, stream);
  prep_kernel<<<NN, 256, 0, stream>>>(z1, z2, zb, pos);
  lse_kernel<<<NBLK, 256, 0, stream>>>(zb, part);
  reduce_kernel<<<TWO_N / 256, 256, 0, stream>>>(part, rowsum);
  finalize_kernel<<<1, 256, 0, stream>>>(rowsum, pos, out);
}

// Round 8
// 127.837 us; speedup vs baseline: 1.1003x; 1.0778x over previous
//
#include <hip/hip_runtime.h>
#include <hip/hip_bf16.h>

// InfoNCE loss, N=4096, D=1024, TEMP=0.07.
// loss = mean_i( -pos_i + lse_i ), lse over sim rows with diagonal masked.
// Fixed-max LSE (rows unit-norm -> sim <= 1/T): partials are order-independent.
// Symmetry via 128x128 tiles, upper triangle (J >= I).
//
// R8: occupancy push. 128x128 tile, 4 waves (2x2), 64x64 out/wave (acc=64
// regs -> ~140 regs/wave -> 3 waves/SIMD), ring-of-3 BK=32 slots = 48 KiB
// -> 3 blocks/CU = 12 waves/CU. Counted vmcnt(4) gate, one s_barrier/step,
// zero-conflict XOR swizzle (verified R5/R7), plane-store epilogue (no
// atomics in hot kernel), reduce+finalize fused.

typedef __attribute__((ext_vector_type(8))) short bf16x8;
typedef __attribute__((ext_vector_type(4))) float f32x4;

#define NN 4096
#define TWO_N 8192
#define DIM 1024
#define TEMP_INV 14.285714285714286f
#define EXP_SCALE 20.609929155566303f /* log2(e)/0.07 */
#define NT 64     /* tiles of 128 per dim */
#define NBLK 2080 /* 64*65/2 upper-tri tiles; 2080 % 8 == 0 -> bijective */
#define SLOT 8192 /* shorts per slot: A 128x32 + B 128x32 (16 KB) */
#define NPLANE 256

#define GLD16(g, l)                                                          \
  __builtin_amdgcn_global_load_lds(                                          \
      (const __attribute__((address_space(1))) void*)(g),                    \
      (__attribute__((address_space(3))) void*)(l), 16, 0, 0)

__device__ __forceinline__ unsigned short f2bf(float f) {
  unsigned int u = __float_as_uint(f);
  u += 0x7fffu + ((u >> 16) & 1u);  // RNE
  return (unsigned short)(u >> 16);
}

// Fused: fp32->bf16 cast of z=[z1;z2] AND pos[row]=dot(z1,z2)/T (one 32MB read).
__global__ __launch_bounds__(256) void prep_kernel(
    const float* __restrict__ z1, const float* __restrict__ z2,
    unsigned short* __restrict__ zb, float* __restrict__ pos) {
  const int row = blockIdx.x, t = threadIdx.x;
  float4 a = ((const float4*)(z1 + (size_t)row * DIM))[t];
  float4 b = ((const float4*)(z2 + (size_t)row * DIM))[t];
  ushort4 ua = {f2bf(a.x), f2bf(a.y), f2bf(a.z), f2bf(a.w)};
  ushort4 ub = {f2bf(b.x), f2bf(b.y), f2bf(b.z), f2bf(b.w)};
  ((ushort4*)(zb + (size_t)row * DIM))[t] = ua;
  ((ushort4*)(zb + (size_t)(NN + row) * DIM))[t] = ub;
  float s = a.x * b.x + a.y * b.y + a.z * b.z + a.w * b.w;
#pragma unroll
  for (int off = 1; off < 64; off <<= 1) s += __shfl_xor(s, off);
  __shared__ float tmp[4];
  if ((t & 63) == 0) tmp[t >> 6] = s;
  __syncthreads();
  if (t == 0) pos[row] = (tmp[0] + tmp[1] + tmp[2] + tmp[3]) * TEMP_INV;
}

__global__ __launch_bounds__(256, 3) void lse_kernel(
    const unsigned short* __restrict__ zb, float* __restrict__ part) {
  __shared__ unsigned short lds[3 * SLOT];  // 48 KiB -> 3 blocks/CU
  // ---- tile decode: XCD swizzle -> upper-tri (I, J), J >= I ----
  int u = ((int)blockIdx.x & 7) * (NBLK / 8) + ((int)blockIdx.x >> 3);
  int I = 0, rem = u;
  while (rem >= NT - I) { rem -= NT - I; ++I; }
  const int J = I + rem;
  const int rowA0 = I * 128, colB0 = J * 128;
  const bool diag = (I == J);

  const int t = threadIdx.x;
  const int wave = t >> 6, lane = t & 63;
  const int wm = wave >> 1, wn = wave & 1;  // 2x2 waves, each 64x64 out
  const int lo = lane & 15, hi = lane >> 4;

  // ---- staging: 2 A-chunks + 2 B-chunks (16B each) per thread per slot ----
  // slot layout (shorts): A[128 rows][32] at 0, B[128][32] at 4096. Chunk c
  // (16B): row=c>>2, phys group p=c&3 holds logical lg = p ^ ((row>>1)&3)
  // (inverse of the read-side XOR). LDS dest linear (wave-uniform + lane*16).
  int oA[2], oB[2];
#pragma unroll
  for (int i = 0; i < 2; ++i) {
    int c = i * 256 + wave * 64 + lane, row = c >> 2, p = c & 3;
    oA[i] = (rowA0 + row) * DIM + (p ^ ((row >> 1) & 3)) * 8;
    oB[i] = (colB0 + row) * DIM + (p ^ ((row >> 1) & 3)) * 8;
  }

  // ---- compute-side ds_read offsets (shorts), swizzle applied on read ----
  const int sx = (hi ^ ((lo >> 1) & 3)) * 8;  // swizzled 16B group
  const int arow0 = wm * 64 + lo;             // + m*16
  const int brow0 = wn * 64 + lo;             // + n*16

  f32x4 acc[4][4];
#pragma unroll
  for (int m = 0; m < 4; ++m)
#pragma unroll
    for (int n = 0; n < 4; ++n) acc[m][n] = (f32x4){0.f, 0.f, 0.f, 0.f};

#define STAGE(dst_, k_)                                                       \
  {                                                                           \
    const unsigned short* gk = zb + (size_t)((k_) & 31) * 32;                 \
    GLD16(gk + oA[0], (dst_) + wave * 512);                                   \
    GLD16(gk + oA[1], (dst_) + 2048 + wave * 512);                            \
    GLD16(gk + oB[0], (dst_) + 4096 + wave * 512);                            \
    GLD16(gk + oB[1], (dst_) + 4096 + 2048 + wave * 512);                     \
  }

  unsigned short* s0 = lds;             // slot s (current)
  unsigned short* s1 = lds + SLOT;      // slot s+1
  unsigned short* s2 = lds + 2 * SLOT;  // slot s+2 (stage target)

  STAGE(s0, 0);
  STAGE(s1, 1);

#pragma unroll 1
  for (int s = 0; s < DIM / 32; ++s) {
    // gate: 4 newest (slot s+1) may stay in flight; slot s must be landed.
    asm volatile("s_waitcnt vmcnt(4)" ::: "memory");
    asm volatile("s_waitcnt lgkmcnt(0)" ::: "memory");  // prev frag reads done
    __builtin_amdgcn_s_barrier();  // publishes slot s; frees slot s-1 (=s2)
    __builtin_amdgcn_sched_barrier(0);
    STAGE(s2, s + 2);  // s>=30: dummy re-stage (k wraps), data never read

    bf16x8 bg[4];
#pragma unroll
    for (int n = 0; n < 4; ++n)
      bg[n] = *(const bf16x8*)(s0 + 4096 + (brow0 + n * 16) * 32 + sx);
    __builtin_amdgcn_s_setprio(1);
#pragma unroll
    for (int m = 0; m < 4; ++m) {
      bf16x8 af = *(const bf16x8*)(s0 + (arow0 + m * 16) * 32 + sx);
#pragma unroll
      for (int n = 0; n < 4; ++n)
        acc[m][n] = __builtin_amdgcn_mfma_f32_16x16x32_bf16(af, bg[n], acc[m][n], 0, 0, 0);
    }
    __builtin_amdgcn_s_setprio(0);
    unsigned short* tmp_ = s0; s0 = s1; s1 = s2; s2 = tmp_;  // rotate ring
  }
  asm volatile("s_waitcnt vmcnt(0) lgkmcnt(0)" ::: "memory");  // drain dummies

  // ---- epilogue: e=exp((dot-1)/T), diag masked; row/col partial sums ----
  // NO atomics: plain stores to tile-private planes (disjoint by construction:
  // row partials keyed by (J,wn); col partials keyed by (I,wm)).
  float* rplane = part + (size_t)(2 * J + wn) * TWO_N;
  float* cplane = part + (size_t)(128 + 2 * I + wm) * TWO_N;
  float csum[4] = {0.f, 0.f, 0.f, 0.f};
#pragma unroll
  for (int m = 0; m < 4; ++m) {
#pragma unroll
    for (int r = 0; r < 4; ++r) {
      const int grow = rowA0 + wm * 64 + m * 16 + hi * 4 + r;  // row=(lane>>4)*4+reg
      float s = 0.f;
#pragma unroll
      for (int n = 0; n < 4; ++n) {
        const int gcol = colB0 + wn * 64 + n * 16 + lo;        // col=lane&15
        float e = exp2f((acc[m][n][r] - 1.0f) * EXP_SCALE);
        if (grow == gcol) e = 0.f;  // mask self-similarity (diag tiles)
        s += e;
        csum[n] += e;
      }
      s += __shfl_xor(s, 1); s += __shfl_xor(s, 2);
      s += __shfl_xor(s, 4); s += __shfl_xor(s, 8);
      if (lo == 0) rplane[grow] = s;  // 4 lanes, 64 distinct rows per wave
    }
  }
  if (!diag) {  // off-diagonal tiles feed transposed rows via col sums
#pragma unroll
    for (int n = 0; n < 4; ++n) {
      float s = csum[n];
      s += __shfl_xor(s, 16); s += __shfl_xor(s, 32);
      if (hi == 0) cplane[colB0 + wn * 64 + n * 16 + lo] = s;  // 16 lanes
    }
  }
#undef STAGE
}

// Fold 256 partial planes -> per-row term -> mean, in one kernel.
// 32 blocks x 256 threads, one row each; out must be zeroed before launch.
__global__ __launch_bounds__(256) void reduce_finalize_kernel(
    const float* __restrict__ part, const float* __restrict__ pos,
    float* __restrict__ out) {
  const int i = blockIdx.x * 256 + threadIdx.x;
  float s = 0.f;
#pragma unroll 8
  for (int p = 0; p < NPLANE; ++p) s += part[(size_t)p * TWO_N + i];
  float term = TEMP_INV + logf(s) - pos[i & (NN - 1)];
#pragma unroll
  for (int off = 1; off < 64; off <<= 1) term += __shfl_xor(term, off);
  __shared__ float tmp[4];
  const int t = threadIdx.x;
  if ((t & 63) == 0) tmp[t >> 6] = term;
  __syncthreads();
  if (t == 0)
    atomicAdd(out, (tmp[0] + tmp[1] + tmp[2] + tmp[3]) * (1.0f / (float)TWO_N));
}

extern "C" void kernel_launch(void* const* d_in, const int* in_sizes, int n_in,
                              void* d_out, int out_size, void* d_ws, size_t ws_size,
                              hipStream_t stream) {
  const float* z1 = (const float*)d_in[0];
  const float* z2 = (const float*)d_in[1];
  float* out = (float*)d_out;

  char* ws = (char*)d_ws;
  unsigned short* zb = (unsigned short*)ws;            // 16 MB bf16 z
  size_t off = (size_t)TWO_N * DIM * 2;
  float* part = (float*)(ws + off);                    // 8 MB: 256 x 8192 f32
  off += (size_t)NPLANE * TWO_N * 4;
  float* pos = (float*)(ws + off);                     // 16 KB

  hipMemsetAsync(part, 0, (size_t)NPLANE * TWO_N * 4, stream);
  hipMemsetAsync(out, 0, sizeof(float), stream);
  prep_kernel<<<NN, 256, 0, stream>>>(z1, z2, zb, pos);
  lse_kernel<<<NBLK, 256, 0, stream>>>(zb, part);
  reduce_finalize_kernel<<<TWO_N / 256, 256, 0, stream>>>(part, pos, out);
}